// Round 1
// baseline (1690.910 us; speedup 1.0000x reference)
//
#include <hip/hip_runtime.h>
#include <cstdint>

static constexpr int B_  = 8;
static constexpr int C_  = 64;
static constexpr int N_  = 65536;
static constexpr int Rr  = 32;
static constexpr int R3  = Rr * Rr * Rr;

// ---------------- kernel 1: per-(batch,axis) mean over N ----------------
__global__ void mean_kernel(const float* __restrict__ coords,
                            float* __restrict__ mean_out) {
    const int ba = blockIdx.x;                       // [0, B*3)
    const float* p = coords + (size_t)ba * N_;
    float s = 0.f;
    for (int i = threadIdx.x; i < N_; i += blockDim.x) s += p[i];
    #pragma unroll
    for (int off = 32; off >= 1; off >>= 1) s += __shfl_down(s, off, 64);
    __shared__ float sm[4];
    const int lane = threadIdx.x & 63, wave = threadIdx.x >> 6;
    if (lane == 0) sm[wave] = s;
    __syncthreads();
    if (threadIdx.x == 0) {
        float t = sm[0] + sm[1] + sm[2] + sm[3];
        mean_out[ba] = t / (float)N_;
    }
}

// ---------------- kernel 2: per-batch max norm ----------------
__global__ void maxnorm_kernel(const float* __restrict__ coords,
                               const float* __restrict__ mean,
                               float* __restrict__ maxn) {
    const int b = blockIdx.x;                        // [0, B)
    const float* p = coords + (size_t)b * 3 * N_;
    const float mx = mean[b * 3 + 0];
    const float my = mean[b * 3 + 1];
    const float mz = mean[b * 3 + 2];
    float m = 0.f;
    for (int i = threadIdx.x; i < N_; i += blockDim.x) {
        const float x = p[i] - mx;
        const float y = p[N_ + i] - my;
        const float z = p[2 * N_ + i] - mz;
        const float n2 = x * x + y * y + z * z;
        m = fmaxf(m, n2);
    }
    #pragma unroll
    for (int off = 32; off >= 1; off >>= 1) m = fmaxf(m, __shfl_down(m, off, 64));
    __shared__ float sm[16];
    const int lane = threadIdx.x & 63, wave = threadIdx.x >> 6;
    if (lane == 0) sm[wave] = m;
    __syncthreads();
    if (threadIdx.x == 0) {
        float t = sm[0];
        const int nw = blockDim.x >> 6;
        for (int w = 1; w < nw; ++w) t = fmaxf(t, sm[w]);
        maxn[b] = sqrtf(t);                          // sqrt(max(n2)) == max(sqrt(n2))
    }
}

// ---------------- kernel 3: voxelize + scatter-add ----------------
__global__ void scatter_kernel(const float* __restrict__ coords,
                               const float* __restrict__ features,
                               const float* __restrict__ mean,
                               const float* __restrict__ maxn,
                               float* __restrict__ out,      // [B,C,R^3], pre-zeroed
                               float* __restrict__ nc_out,   // [B,3,N]
                               float* __restrict__ counts) { // [B,R^3], pre-zeroed
    const int idx = blockIdx.x * blockDim.x + threadIdx.x;
    if (idx >= B_ * N_) return;
    const int b = idx >> 16;            // idx / N_
    const int n = idx & (N_ - 1);

    const float* pc = coords + (size_t)b * 3 * N_;
    const float denom = 2.0f * maxn[b];   // EPS == 0
    int flat = 0;
    #pragma unroll
    for (int a = 0; a < 3; ++a) {
        // same op order as reference: (c - mean)/denom + 0.5, *R, clip, round
        float v = (pc[(size_t)a * N_ + n] - mean[b * 3 + a]) / denom + 0.5f;
        v = v * (float)Rr;
        v = fminf(fmaxf(v, 0.0f), (float)(Rr - 1));
        nc_out[(size_t)b * 3 * N_ + (size_t)a * N_ + n] = v;
        flat = flat * Rr + (int)rintf(v);   // round half to even == jnp.round
    }

    atomicAdd(&counts[b * R3 + flat], 1.0f);

    const float* pf = features + (size_t)b * C_ * N_ + n;
    float* po = out + (size_t)b * C_ * R3 + flat;
    #pragma unroll 4
    for (int c = 0; c < C_; ++c) {
        atomicAdd(po + (size_t)c * R3, pf[(size_t)c * N_]);
    }
}

// ---------------- kernel 4: divide by max(count,1) ----------------
__global__ void finalize_kernel(float* __restrict__ out,
                                const float* __restrict__ counts) {
    const int idx = blockIdx.x * blockDim.x + threadIdx.x;
    if (idx >= B_ * C_ * R3) return;
    const int b = idx / (C_ * R3);
    const int v = idx & (R3 - 1);
    const float cnt = counts[b * R3 + v];
    out[idx] = out[idx] / fmaxf(cnt, 1.0f);
}

extern "C" void kernel_launch(void* const* d_in, const int* in_sizes, int n_in,
                              void* d_out, int out_size, void* d_ws, size_t ws_size,
                              hipStream_t stream) {
    const float* features = (const float*)d_in[0];   // [B,C,N]
    const float* coords   = (const float*)d_in[1];   // [B,3,N]

    float* out    = (float*)d_out;                   // [B,C,R,R,R]
    float* nc_out = out + (size_t)B_ * C_ * R3;      // [B,3,N]

    float* counts = (float*)d_ws;                    // B*R3 floats
    float* mean   = counts + (size_t)B_ * R3;        // B*3 floats
    float* maxn   = mean + B_ * 3;                   // B floats

    // zero the accumulation targets (harness poisons, does not re-zero)
    hipMemsetAsync(d_out, 0, (size_t)B_ * C_ * R3 * sizeof(float), stream);
    hipMemsetAsync(d_ws, 0, ((size_t)B_ * R3 + B_ * 3 + B_) * sizeof(float), stream);

    mean_kernel<<<B_ * 3, 256, 0, stream>>>(coords, mean);
    maxnorm_kernel<<<B_, 1024, 0, stream>>>(coords, mean, maxn);

    const int pts = B_ * N_;
    scatter_kernel<<<(pts + 255) / 256, 256, 0, stream>>>(
        coords, features, mean, maxn, out, nc_out, counts);

    const int tot = B_ * C_ * R3;
    finalize_kernel<<<(tot + 255) / 256, 256, 0, stream>>>(out, counts);
}